// Round 18
// baseline (247.943 us; speedup 1.0000x reference)
//
#include <hip/hip_runtime.h>

#define N_NODES 50000
#define N_EDGES 100000
#define DD 32
#define STEPS 5
#define ETYPES 8
#define CAP_T 13312              // per-type slot capacity (mult of 64; mean 12500, sigma~105)
#define CAP (ETYPES * CAP_T)     // 106496 sorted slots
#define TRASH N_EDGES            // trash row index in fea_in (extra row allocated)
#define SCAN_B 49                // 49 blocks * 1024 = 50176 >= N_NODES
#define NSB 256                  // src-blocks per type (src>>8 in 0..195)

#define GRU_GRID ((N_NODES / 16 + 3) / 4)      // 782 blocks of 4 waves (3125 waves)

typedef float f32x4v __attribute__((ext_vector_type(4)));
typedef short s16x8 __attribute__((ext_vector_type(8))); // 8 bf16 (4 VGPRs)
typedef ushort u16x8 __attribute__((ext_vector_type(8)));
typedef unsigned long long u64;

__device__ __forceinline__ ushort f2bf(float x) {        // fp32 -> bf16 RNE
    unsigned u = __float_as_uint(x);
    u += 0x7fff + ((u >> 16) & 1);
    return (ushort)(u >> 16);
}
__device__ __forceinline__ float bf2f(ushort h) {
    return __uint_as_float(((unsigned)h) << 16);
}
__device__ __forceinline__ void mk_split(const float* v, s16x8& h, s16x8& lo) {
#pragma unroll
    for (int i = 0; i < 8; ++i) {
        ushort hi = f2bf(v[i]);
        h[i] = (short)hi;
        lo[i] = (short)f2bf(v[i] - bf2f(hi));
    }
}
__device__ __forceinline__ float sigm(float x) {
    return 1.f / (1.f + __expf(-x));
}
__device__ __forceinline__ float fast_tanh(float x) {
    x = fminf(fmaxf(x, -15.f), 15.f);
    float e = __expf(2.f * x);
    return (e - 1.f) / (e + 1.f);
}

// prop[n,j] = emb[token[n],j]; zero cnt_in/tsb/c8; dummy-init sorted slots.
__global__ void init_kernel(const int* __restrict__ token,
                            const float* __restrict__ emb,
                            float* __restrict__ prop,
                            int* __restrict__ cnt,      // N + ETYPES*NSB
                            u64* __restrict__ c8,
                            int* __restrict__ se,
                            int* __restrict__ spi) {
    int idx = blockIdx.x * 256 + threadIdx.x;   // over N*D = 1.6M, exact grid
    int n = idx >> 5, j = idx & 31;
    prop[idx] = emb[token[n] * DD + j];
    if (idx < N_NODES + ETYPES * NSB) cnt[idx] = 0;
    if (idx < N_NODES) c8[idx] = 0ull;
    if (idx < CAP) { se[idx] = 0; spi[idx] = TRASH; }
}

// W_edge MFMA B-fragments (split bf16, deinterleaved: n<32 fwd, n>=32 rev)
// + W_r|W_z|W_t fragments. B-frag: lane l holds col (nt*16 + l&15),
// k = kt*32 + (l>>4)*8 + i.
__global__ __launch_bounds__(256) void
wfrag_kernel(const float* __restrict__ W_edge,
             const float* __restrict__ W_r, const float* __restrict__ W_z,
             const float* __restrict__ W_t,
             ushort* __restrict__ wfh, ushort* __restrict__ wfl,
             ushort* __restrict__ wgh, ushort* __restrict__ wgl) {
    int idx = blockIdx.x * 256 + threadIdx.x;      // 2048 + 1152 threads
    if (idx < ETYPES * 4 * 64) {
        int t  = idx >> 8;
        int nt = (idx >> 6) & 3;
        int l  = idx & 63;
        int n  = nt * 16 + (l & 15);               // 0..63 deinterleaved col
        int j  = n & 31;
        int p  = n >> 5;                           // 0: fwd, 1: rev
#pragma unroll
        for (int i = 0; i < 8; ++i) {
            int k = (l >> 4) * 8 + i;
            float v = W_edge[(((size_t)t * DD + k) * DD + j) * 2 + p];
            ushort hi = f2bf(v);
            int o = ((t * 4 + nt) * 64 + l) * 8 + i;
            wfh[o] = hi;
            wfl[o] = f2bf(v - bf2f(hi));
        }
    } else if (idx < ETYPES * 4 * 64 + 1152) {
        int x = idx - ETYPES * 4 * 64;
        int g  = x / 384;
        int kt = (x / 128) % 3;
        int nt = (x / 64) % 2;
        int l  = x & 63;
        const float* W = g == 0 ? W_r : (g == 1 ? W_z : W_t);
        int col = nt * 16 + (l & 15);
#pragma unroll
        for (int i = 0; i < 8; ++i) {
            int k = kt * 32 + (l >> 4) * 8 + i;
            float v = W[k * DD + col];
            ushort hi = f2bf(v);
            int o = (((g * 3 + kt) * 2 + nt) * 64 + l) * 8 + i;
            wgh[o] = hi;
            wgl[o] = f2bf(v - bf2f(hi));
        }
    }
}

// One pass over edges: in-ranks, packed out-type counts, and (type, src>>8)
// bucket ranks for the src-locality sort (global counters, ~49 hits each).
__global__ void hist_kernel(const int* __restrict__ etype,
                            const int* __restrict__ src,
                            const int* __restrict__ dst,
                            int* __restrict__ cnt_in, int* __restrict__ tsb,
                            u64* __restrict__ c8,
                            int* __restrict__ rank_in, int* __restrict__ rb) {
    int e = blockIdx.x * 256 + threadIdx.x;
    if (e < N_EDGES) {
        int t = etype[e];
        int s = src[e];
        rank_in[e] = atomicAdd(&cnt_in[dst[e]], 1);
        rb[e] = atomicAdd(&tsb[t * NSB + (s >> 8)], 1);
        atomicAdd(&c8[s], 1ull << (8 * t));          // out-edge type count
    }
}

// Segmented exclusive scan of the 8x256 (type, src-block) counters; restart
// at each type boundary. One block: 256 threads x 8 counters each (chunks
// never straddle a type: 32 threads per type, aligned).
__global__ __launch_bounds__(256) void
scanT(const int* __restrict__ tsb, int* __restrict__ qoff) {
    __shared__ int s[256];
    __shared__ int tstart[ETYPES];
    int ti = threadIdx.x;
    int base = ti * 8;
    int loc[8];
    int ls = 0;
#pragma unroll
    for (int i = 0; i < 8; ++i) { loc[i] = ls; ls += tsb[base + i]; }
    s[ti] = ls;
    __syncthreads();
    for (int ofs = 1; ofs < 256; ofs <<= 1) {
        int u = (ti >= ofs) ? s[ti - ofs] : 0;
        __syncthreads();
        s[ti] += u;
        __syncthreads();
    }
    int ebase = s[ti] - ls;                          // exclusive base
    if ((ti & 31) == 0) tstart[ti >> 5] = ebase;     // type-start running total
    __syncthreads();
    int tb = tstart[ti >> 5];
#pragma unroll
    for (int i = 0; i < 8; ++i) qoff[base + i] = ebase + loc[i] - tb;
}

// Scan stage 1: block-local exclusive scan of cnt_in (coalesced, wide).
__global__ __launch_bounds__(1024) void
scan1(const int* __restrict__ cnt_in, int* __restrict__ off_in,
      int* __restrict__ bsum) {
    __shared__ int s[1024];
    int i = blockIdx.x * 1024 + threadIdx.x;
    int x = (i < N_NODES) ? cnt_in[i] : 0;
    s[threadIdx.x] = x;
    __syncthreads();
    for (int ofs = 1; ofs < 1024; ofs <<= 1) {
        int u = (threadIdx.x >= ofs) ? s[threadIdx.x - ofs] : 0;
        __syncthreads();
        s[threadIdx.x] += u;
        __syncthreads();
    }
    if (i < N_NODES) off_in[i] = s[threadIdx.x] - x;   // local exclusive
    if (threadIdx.x == 1023) bsum[blockIdx.x] = s[1023];
}

// Stage 2: scan 49 block sums (one 64-thread block).
__global__ void scan2(const int* __restrict__ bsum, int* __restrict__ ebase,
                      int* __restrict__ off_in) {
    __shared__ int s[64];
    int t = threadIdx.x;
    int x = (t < SCAN_B) ? bsum[t] : 0;
    s[t] = x;
    __syncthreads();
    for (int ofs = 1; ofs < 64; ofs <<= 1) {
        int u = (t >= ofs) ? s[t - ofs] : 0;
        __syncthreads();
        s[t] += u;
        __syncthreads();
    }
    if (t < SCAN_B) ebase[t] = s[t] - x;
    if (t == 0) off_in[N_NODES] = N_EDGES;
}

// Stage 3: add scanned block bases.
__global__ __launch_bounds__(1024) void
scan3(int* __restrict__ off_in, const int* __restrict__ ebase) {
    int i = blockIdx.x * 1024 + threadIdx.x;
    if (i < N_NODES) off_in[i] += ebase[blockIdx.x];
}

// Scatter edge records into (type, src-block)-sorted slots with in-CSR pos.
__global__ void place_kernel(const int* __restrict__ etype,
                             const int* __restrict__ src,
                             const int* __restrict__ dst,
                             const int* __restrict__ in_off,
                             const int* __restrict__ rank_in,
                             const int* __restrict__ rb,
                             const int* __restrict__ qoff,
                             int* __restrict__ se, int* __restrict__ spi) {
    int e = blockIdx.x * 256 + threadIdx.x;
    if (e < N_EDGES) {
        int t = etype[e];
        int s = src[e];
        int q = t * CAP_T + qoff[t * NSB + (s >> 8)] + rb[e];
        if (q < CAP) {                          // guard: never OOB even on 8-sigma
            se[q]  = s;
            spi[q] = in_off[dst[e]] + rank_in[e];
        }
    }
}

// MFMA edge kernel, FWD ONLY, bf16 OUTPUT. Wave = 16 same-type edges
// (src-block sorted: the 16 prop gathers fall in one <=32KB window, often
// duplicated rows -> L1 hits). D[16x32] = H[16x32] @ Wfwd[32x32],
// 2 n-tiles x 3-split = 6 MFMA. C/D layout (m89): row=(l>>4)*4+reg, col=l&15.
__global__ __launch_bounds__(256) void
edge_kernel(const int* __restrict__ se, const int* __restrict__ spi,
            const ushort* __restrict__ wfh, const ushort* __restrict__ wfl,
            const float* __restrict__ prop,
            ushort* __restrict__ fea_in) {
    int wv = blockIdx.x * 4 + (threadIdx.x >> 6);   // wave id; 16 edges each
    int l  = threadIdx.x & 63;
    int slot0 = wv * 16;
    int type = slot0 / CAP_T;                       // wave-uniform (CAP_T%16==0)
    int m  = l & 15;
    int kb = l >> 4;

    // A fragment: h[slot0+m][kb*8 .. kb*8+7] -> split bf16
    int sm = se[slot0 + m];
    const float4* p4 = (const float4*)prop;
    float4 h0 = p4[(size_t)sm * 8 + kb * 2];
    float4 h1 = p4[(size_t)sm * 8 + kb * 2 + 1];
    float hv[8] = {h0.x, h0.y, h0.z, h0.w, h1.x, h1.y, h1.z, h1.w};
    s16x8 ah, al;
    mk_split(hv, ah, al);

    int pr[4];
#pragma unroll
    for (int reg = 0; reg < 4; ++reg) pr[reg] = spi[slot0 + kb * 4 + reg];

    const s16x8* bh8 = (const s16x8*)wfh;
    const s16x8* bl8 = (const s16x8*)wfl;
    f32x4v acc[2];
#pragma unroll
    for (int nt = 0; nt < 2; ++nt) {                // fwd tiles only
        s16x8 bh = bh8[(type * 4 + nt) * 64 + l];
        s16x8 bl = bl8[(type * 4 + nt) * 64 + l];
        f32x4v a = {0.f, 0.f, 0.f, 0.f};
        a = __builtin_amdgcn_mfma_f32_16x16x32_bf16(ah, bh, a, 0, 0, 0);
        a = __builtin_amdgcn_mfma_f32_16x16x32_bf16(al, bh, a, 0, 0, 0);
        a = __builtin_amdgcn_mfma_f32_16x16x32_bf16(ah, bl, a, 0, 0, 0);
        acc[nt] = a;
    }
#pragma unroll
    for (int nt = 0; nt < 2; ++nt)
#pragma unroll
        for (int reg = 0; reg < 4; ++reg)
            fea_in[(size_t)pr[reg] * DD + nt * 16 + m] = f2bf(acc[nt][reg]);
}

// MFMA GRU with factorized out-sums, bf16 in-gather (R17, proven 232.8us).
__global__ __launch_bounds__(256) void
gru_kernel(const ushort* __restrict__ wgh, const ushort* __restrict__ wgl,
           const ushort* __restrict__ wfh, const ushort* __restrict__ wfl,
           const float* __restrict__ b_r, const float* __restrict__ b_z,
           const float* __restrict__ b_t,
           const ushort* __restrict__ fea_in,
           const int* __restrict__ in_off,
           const u64* __restrict__ c8,
           float* __restrict__ prop,
           float* __restrict__ out2) {
    __shared__ float tr[4][16 * 36];                  // per-wave transpose pad
    const int wvl = threadIdx.x >> 6;
    const int wv = blockIdx.x * 4 + wvl;
    if (wv * 16 >= N_NODES) return;                   // 3125 waves exact
    const int l = threadIdx.x & 63;
    const int m = l & 15;
    const int kb = l >> 4;
    const int gn = wv * 16 + m;                       // A-row node

    // ---- issue long-latency loads first ----
    int i0 = in_off[gn], i1 = in_off[gn + 1];
    u64 cb[4];
#pragma unroll
    for (int reg = 0; reg < 4; ++reg) cb[reg] = c8[wv * 16 + kb * 4 + reg];
    float pA[8];
    {
        const float4* p4 = (const float4*)prop;
        float4 a = p4[(size_t)gn * 8 + kb * 2];
        float4 b = p4[(size_t)gn * 8 + kb * 2 + 1];
        pA[0] = a.x; pA[1] = a.y; pA[2] = a.z; pA[3] = a.w;
        pA[4] = b.x; pA[5] = b.y; pA[6] = b.z; pA[7] = b.w;
    }
    s16x8 ph, pl;
    mk_split(pA, ph, pl);

    // ---- dense out-sum: 8 types, c-weighted, on the prop fragment ----
    const s16x8* eh8 = (const s16x8*)wfh;
    const s16x8* el8 = (const s16x8*)wfl;
    f32x4v outD[2];
    outD[0] = (f32x4v){0.f, 0.f, 0.f, 0.f};
    outD[1] = (f32x4v){0.f, 0.f, 0.f, 0.f};
#pragma unroll 1
    for (int t = 0; t < ETYPES; ++t) {
        s16x8 bh2 = eh8[(t * 4 + 2) * 64 + l];        // rev tiles of W_edge
        s16x8 bl2 = el8[(t * 4 + 2) * 64 + l];
        s16x8 bh3 = eh8[(t * 4 + 3) * 64 + l];
        s16x8 bl3 = el8[(t * 4 + 3) * 64 + l];
        f32x4v a0 = {0.f, 0.f, 0.f, 0.f}, a1 = {0.f, 0.f, 0.f, 0.f};
        a0 = __builtin_amdgcn_mfma_f32_16x16x32_bf16(ph, bh2, a0, 0, 0, 0);
        a0 = __builtin_amdgcn_mfma_f32_16x16x32_bf16(pl, bh2, a0, 0, 0, 0);
        a0 = __builtin_amdgcn_mfma_f32_16x16x32_bf16(ph, bl2, a0, 0, 0, 0);
        a1 = __builtin_amdgcn_mfma_f32_16x16x32_bf16(ph, bh3, a1, 0, 0, 0);
        a1 = __builtin_amdgcn_mfma_f32_16x16x32_bf16(pl, bh3, a1, 0, 0, 0);
        a1 = __builtin_amdgcn_mfma_f32_16x16x32_bf16(ph, bl3, a1, 0, 0, 0);
#pragma unroll
        for (int reg = 0; reg < 4; ++reg) {
            float w = (float)((cb[reg] >> (8 * t)) & 0xff);
            outD[0][reg] = fmaf(w, a0[reg], outD[0][reg]);
            outD[1][reg] = fmaf(w, a1[reg], outD[1][reg]);
        }
    }

    // ---- CSR-gather in-sum (bf16 rows, one 16B load per row) ----
    float va[8];
#pragma unroll
    for (int i = 0; i < 8; ++i) va[i] = 0.f;
    {
        const u16x8* fi8 = (const u16x8*)fea_in;      // row = 4 x ushort8
        for (int r = i0; r < i1; ++r) {
            u16x8 x = fi8[(size_t)r * 4 + kb];
#pragma unroll
            for (int i = 0; i < 8; ++i) va[i] += bf2f(x[i]);
        }
    }

    // ---- transpose out (D-layout -> A-layout) via per-wave LDS ----
    float* T = tr[wvl];
#pragma unroll
    for (int nt = 0; nt < 2; ++nt)
#pragma unroll
        for (int reg = 0; reg < 4; ++reg)
            T[(kb * 4 + reg) * 36 + nt * 16 + m] = outD[nt][reg];
    float oA[8];
    {
        const float4* T4 = (const float4*)(T + m * 36 + kb * 8);
        float4 x = T4[0], y = T4[1];
        oA[0] = x.x; oA[1] = x.y; oA[2] = x.z; oA[3] = x.w;
        oA[4] = y.x; oA[5] = y.y; oA[6] = y.z; oA[7] = y.w;
    }

    s16x8 ah[3], al[3];
    mk_split(va, ah[0], al[0]);
    mk_split(oA, ah[1], al[1]);
    ah[2] = ph; al[2] = pl;

    const s16x8* bh8 = (const s16x8*)wgh;
    const s16x8* bl8 = (const s16x8*)wgl;
    f32x4v ar[2], az[2], at_[2];
#pragma unroll
    for (int nt = 0; nt < 2; ++nt) {
        ar[nt] = (f32x4v){0.f, 0.f, 0.f, 0.f};
        az[nt] = (f32x4v){0.f, 0.f, 0.f, 0.f};
        at_[nt] = (f32x4v){0.f, 0.f, 0.f, 0.f};
    }
#pragma unroll
    for (int nt = 0; nt < 2; ++nt) {
#pragma unroll
        for (int kt = 0; kt < 3; ++kt) {
            s16x8 bh = bh8[((0 * 3 + kt) * 2 + nt) * 64 + l];
            s16x8 bl = bl8[((0 * 3 + kt) * 2 + nt) * 64 + l];
            ar[nt] = __builtin_amdgcn_mfma_f32_16x16x32_bf16(ah[kt], bh, ar[nt], 0, 0, 0);
            ar[nt] = __builtin_amdgcn_mfma_f32_16x16x32_bf16(al[kt], bh, ar[nt], 0, 0, 0);
            ar[nt] = __builtin_amdgcn_mfma_f32_16x16x32_bf16(ah[kt], bl, ar[nt], 0, 0, 0);
            s16x8 ch = bh8[((1 * 3 + kt) * 2 + nt) * 64 + l];
            s16x8 cl = bl8[((1 * 3 + kt) * 2 + nt) * 64 + l];
            az[nt] = __builtin_amdgcn_mfma_f32_16x16x32_bf16(ah[kt], ch, az[nt], 0, 0, 0);
            az[nt] = __builtin_amdgcn_mfma_f32_16x16x32_bf16(al[kt], ch, az[nt], 0, 0, 0);
            az[nt] = __builtin_amdgcn_mfma_f32_16x16x32_bf16(ah[kt], cl, az[nt], 0, 0, 0);
            if (kt < 2) {
                s16x8 th = bh8[((2 * 3 + kt) * 2 + nt) * 64 + l];
                s16x8 tl = bl8[((2 * 3 + kt) * 2 + nt) * 64 + l];
                at_[nt] = __builtin_amdgcn_mfma_f32_16x16x32_bf16(ah[kt], th, at_[nt], 0, 0, 0);
                at_[nt] = __builtin_amdgcn_mfma_f32_16x16x32_bf16(al[kt], th, at_[nt], 0, 0, 0);
                at_[nt] = __builtin_amdgcn_mfma_f32_16x16x32_bf16(ah[kt], tl, at_[nt], 0, 0, 0);
            }
        }
    }

    // ---- bias + sigmoid; r*p and z in D-layout (row=kb*4+reg, col=nt*16+m) --
    float rv[2][4], zv[2][4], pD[2][4];
#pragma unroll
    for (int nt = 0; nt < 2; ++nt) {
        float br = b_r[nt * 16 + m];
        float bz = b_z[nt * 16 + m];
#pragma unroll
        for (int reg = 0; reg < 4; ++reg) {
            int nd = wv * 16 + kb * 4 + reg;
            pD[nt][reg] = prop[(size_t)nd * DD + nt * 16 + m];
            rv[nt][reg] = sigm(ar[nt][reg] + br) * pD[nt][reg];   // r*p
            zv[nt][reg] = sigm(az[nt][reg] + bz);
        }
    }

    // ---- transpose r*p via the same per-wave LDS pad (in-order DS) ----
#pragma unroll
    for (int nt = 0; nt < 2; ++nt)
#pragma unroll
        for (int reg = 0; reg < 4; ++reg)
            T[(kb * 4 + reg) * 36 + nt * 16 + m] = rv[nt][reg];
    float rpA[8];
    {
        const float4* T4 = (const float4*)(T + m * 36 + kb * 8);
        float4 x = T4[0], y = T4[1];
        rpA[0] = x.x; rpA[1] = x.y; rpA[2] = x.z; rpA[3] = x.w;
        rpA[4] = y.x; rpA[5] = y.y; rpA[6] = y.z; rpA[7] = y.w;
    }
    s16x8 rh, rl;
    mk_split(rpA, rh, rl);
#pragma unroll
    for (int nt = 0; nt < 2; ++nt) {
        s16x8 th = bh8[((2 * 3 + 2) * 2 + nt) * 64 + l];
        s16x8 tl = bl8[((2 * 3 + 2) * 2 + nt) * 64 + l];
        at_[nt] = __builtin_amdgcn_mfma_f32_16x16x32_bf16(rh, th, at_[nt], 0, 0, 0);
        at_[nt] = __builtin_amdgcn_mfma_f32_16x16x32_bf16(rl, th, at_[nt], 0, 0, 0);
        at_[nt] = __builtin_amdgcn_mfma_f32_16x16x32_bf16(rh, tl, at_[nt], 0, 0, 0);
    }

    // ---- update: prop = p + z*(tanh(t) - p); final step writes out2 ONLY ----
#pragma unroll
    for (int nt = 0; nt < 2; ++nt) {
        float bt = b_t[nt * 16 + m];
#pragma unroll
        for (int reg = 0; reg < 4; ++reg) {
            int nd = wv * 16 + kb * 4 + reg;
            float tv = fast_tanh(at_[nt][reg] + bt);
            float o = fmaf(zv[nt][reg], tv - pD[nt][reg], pD[nt][reg]);
            if (out2) out2[(size_t)nd * DD + nt * 16 + m] = o;
            else      prop[(size_t)nd * DD + nt * 16 + m] = o;
        }
    }
}

extern "C" void kernel_launch(void* const* d_in, const int* in_sizes, int n_in,
                              void* d_out, int out_size, void* d_ws, size_t ws_size,
                              hipStream_t stream) {
    const int*   token  = (const int*)d_in[0];
    const int*   etype  = (const int*)d_in[1];
    const int*   src    = (const int*)d_in[2];
    const int*   dst    = (const int*)d_in[3];
    const float* emb    = (const float*)d_in[4];
    const float* W_edge = (const float*)d_in[5];
    const float* W_r    = (const float*)d_in[6];
    const float* b_r    = (const float*)d_in[7];
    const float* W_z    = (const float*)d_in[8];
    const float* b_z    = (const float*)d_in[9];
    const float* W_t    = (const float*)d_in[10];
    const float* b_t    = (const float*)d_in[11];
    float* out = (float*)d_out;

    // Persistent workspace (~15 MB; ws_size = 256 MB per the poison fill):
    float* prop      = (float*)d_ws;                          // N*D floats
    ushort* fea_in   = (ushort*)(prop + (size_t)N_NODES * DD);// (E+1)*D bf16
    ushort* wfh = fea_in + (size_t)(N_EDGES + 1) * DD;        // 16K ushorts
    ushort* wfl = wfh + ETYPES * 4 * 64 * 8;                  // 16K
    ushort* wgh = wfl + ETYPES * 4 * 64 * 8;                  // 9216
    ushort* wgl = wgh + 1152 * 8;                             // 9216
    u64* c8     = (u64*)(wgl + 1152 * 8);                     // N u64 (8B-aligned)
    int* in_off   = (int*)(c8 + N_NODES);                     // N+1
    int* se       = in_off + (N_NODES + 1);                   // CAP
    int* spi      = se + CAP;                                 // CAP

    // Setup temporaries OVERLAID on fea_in (dead before first edge write).
    int* cnt      = (int*)fea_in;                             // N + ETYPES*NSB
    int* cnt_in   = cnt;
    int* tsb      = cnt + N_NODES;                            // ETYPES*NSB
    int* rank_in  = tsb + ETYPES * NSB;                       // E
    int* rb       = rank_in + N_EDGES;                        // E
    int* qoff     = rb + N_EDGES;                             // ETYPES*NSB
    int* bsum     = qoff + ETYPES * NSB;                      // SCAN_B
    int* ebase    = bsum + SCAN_B;                            // SCAN_B

    // per-launch setup: prop init + W fragments + sorted in-CSR build
    init_kernel<<<(N_NODES * DD) / 256, 256, 0, stream>>>(token, emb, prop, cnt,
                                                          c8, se, spi);
    wfrag_kernel<<<13, 256, 0, stream>>>(W_edge, W_r, W_z, W_t,
                                         wfh, wfl, wgh, wgl);
    hist_kernel<<<(N_EDGES + 255) / 256, 256, 0, stream>>>(
        etype, src, dst, cnt_in, tsb, c8, rank_in, rb);
    scanT<<<1, 256, 0, stream>>>(tsb, qoff);
    scan1<<<SCAN_B, 1024, 0, stream>>>(cnt_in, in_off, bsum);
    scan2<<<1, 64, 0, stream>>>(bsum, ebase, in_off);
    scan3<<<SCAN_B, 1024, 0, stream>>>(in_off, ebase);
    place_kernel<<<(N_EDGES + 255) / 256, 256, 0, stream>>>(
        etype, src, dst, in_off, rank_in, rb, qoff, se, spi);

    for (int step = 0; step < STEPS; ++step) {
        edge_kernel<<<CAP / 64, 256, 0, stream>>>(se, spi, wfh, wfl, prop,
                                                  fea_in);
        gru_kernel<<<GRU_GRID, 256, 0, stream>>>(
            wgh, wgl, wfh, wfl, b_r, b_z, b_t, fea_in, in_off, c8,
            prop, (step == STEPS - 1) ? out : nullptr);
    }
}

// Round 19
// 232.028 us; speedup vs baseline: 1.0686x; 1.0686x over previous
//
#include <hip/hip_runtime.h>

#define N_NODES 50000
#define N_EDGES 100000
#define DD 32
#define STEPS 5
#define ETYPES 8
#define CAP_T 13312              // per-type slot capacity (mult of 64; mean 12500, sigma~105)
#define CAP (ETYPES * CAP_T)     // 106496 sorted slots
#define TRASH N_EDGES            // trash row index in fea_in (extra row allocated)
#define SCAN_B 49                // 49 blocks * 1024 = 50176 >= N_NODES

#define GRU_GRID ((N_NODES / 16 + 3) / 4)      // 782 blocks of 4 waves (3125 waves)

typedef float f32x4v __attribute__((ext_vector_type(4)));
typedef short s16x8 __attribute__((ext_vector_type(8))); // 8 bf16 (4 VGPRs)
typedef ushort u16x8 __attribute__((ext_vector_type(8)));
typedef unsigned long long u64;

__device__ __forceinline__ ushort f2bf(float x) {        // fp32 -> bf16 RNE
    unsigned u = __float_as_uint(x);
    u += 0x7fff + ((u >> 16) & 1);
    return (ushort)(u >> 16);
}
__device__ __forceinline__ float bf2f(ushort h) {
    return __uint_as_float(((unsigned)h) << 16);
}
__device__ __forceinline__ void mk_split(const float* v, s16x8& h, s16x8& lo) {
#pragma unroll
    for (int i = 0; i < 8; ++i) {
        ushort hi = f2bf(v[i]);
        h[i] = (short)hi;
        lo[i] = (short)f2bf(v[i] - bf2f(hi));
    }
}
__device__ __forceinline__ float sigm(float x) {
    return 1.f / (1.f + __expf(-x));
}
__device__ __forceinline__ float fast_tanh(float x) {
    x = fminf(fmaxf(x, -15.f), 15.f);
    float e = __expf(2.f * x);
    return (e - 1.f) / (e + 1.f);
}

// prop[n,j] = emb[token[n],j]; zero cnt_in/tcnt/c8; dummy-init sorted slots.
__global__ void init_kernel(const int* __restrict__ token,
                            const float* __restrict__ emb,
                            float* __restrict__ prop,
                            int* __restrict__ cnt,      // N+8: cnt_in | tcnt
                            u64* __restrict__ c8,
                            int* __restrict__ se,
                            int* __restrict__ spi) {
    int idx = blockIdx.x * 256 + threadIdx.x;   // over N*D = 1.6M, exact grid
    int n = idx >> 5, j = idx & 31;
    prop[idx] = emb[token[n] * DD + j];
    if (idx < N_NODES + ETYPES) cnt[idx] = 0;
    if (idx < N_NODES) c8[idx] = 0ull;
    if (idx < CAP) { se[idx] = 0; spi[idx] = TRASH; }
}

// W_edge MFMA B-fragments (split bf16, deinterleaved: n<32 fwd, n>=32 rev)
// + W_r|W_z|W_t fragments. B-frag: lane l holds col (nt*16 + l&15),
// k = kt*32 + (l>>4)*8 + i.
__global__ __launch_bounds__(256) void
wfrag_kernel(const float* __restrict__ W_edge,
             const float* __restrict__ W_r, const float* __restrict__ W_z,
             const float* __restrict__ W_t,
             ushort* __restrict__ wfh, ushort* __restrict__ wfl,
             ushort* __restrict__ wgh, ushort* __restrict__ wgl) {
    int idx = blockIdx.x * 256 + threadIdx.x;      // 2048 + 1152 threads
    if (idx < ETYPES * 4 * 64) {
        int t  = idx >> 8;
        int nt = (idx >> 6) & 3;
        int l  = idx & 63;
        int n  = nt * 16 + (l & 15);               // 0..63 deinterleaved col
        int j  = n & 31;
        int p  = n >> 5;                           // 0: fwd, 1: rev
#pragma unroll
        for (int i = 0; i < 8; ++i) {
            int k = (l >> 4) * 8 + i;
            float v = W_edge[(((size_t)t * DD + k) * DD + j) * 2 + p];
            ushort hi = f2bf(v);
            int o = ((t * 4 + nt) * 64 + l) * 8 + i;
            wfh[o] = hi;
            wfl[o] = f2bf(v - bf2f(hi));
        }
    } else if (idx < ETYPES * 4 * 64 + 1152) {
        int x = idx - ETYPES * 4 * 64;
        int g  = x / 384;
        int kt = (x / 128) % 3;
        int nt = (x / 64) % 2;
        int l  = x & 63;
        const float* W = g == 0 ? W_r : (g == 1 ? W_z : W_t);
        int col = nt * 16 + (l & 15);
#pragma unroll
        for (int i = 0; i < 8; ++i) {
            int k = kt * 32 + (l >> 4) * 8 + i;
            float v = W[k * DD + col];
            ushort hi = f2bf(v);
            int o = (((g * 3 + kt) * 2 + nt) * 64 + l) * 8 + i;
            wgh[o] = hi;
            wgl[o] = f2bf(v - bf2f(hi));
        }
    }
}

// One pass over edges: in-ranks (global atomics), packed out-type counts
// (one u64 atomic per edge), type-bucket slot via block-local LDS histogram.
__global__ void hist_kernel(const int* __restrict__ etype,
                            const int* __restrict__ src,
                            const int* __restrict__ dst,
                            int* __restrict__ cnt_in, int* __restrict__ tcnt,
                            u64* __restrict__ c8,
                            int* __restrict__ rank_in, int* __restrict__ qe) {
    __shared__ int lh[ETYPES], lbase[ETYPES];
    int tid = threadIdx.x;
    int e = blockIdx.x * 256 + tid;
    if (tid < ETYPES) lh[tid] = 0;
    __syncthreads();
    int t = 0, lr = 0;
    bool v = e < N_EDGES;
    if (v) {
        t = etype[e];
        lr = atomicAdd(&lh[t], 1);
        rank_in[e] = atomicAdd(&cnt_in[dst[e]], 1);
        atomicAdd(&c8[src[e]], 1ull << (8 * t));     // out-edge type count
    }
    __syncthreads();
    if (tid < ETYPES) lbase[tid] = atomicAdd(&tcnt[tid], lh[tid]);
    __syncthreads();
    if (v) qe[e] = t * CAP_T + lbase[t] + lr;
}

// Scan stage 1: block-local exclusive scan of cnt_in (coalesced, wide).
__global__ __launch_bounds__(1024) void
scan1(const int* __restrict__ cnt_in, int* __restrict__ off_in,
      int* __restrict__ bsum) {
    __shared__ int s[1024];
    int i = blockIdx.x * 1024 + threadIdx.x;
    int x = (i < N_NODES) ? cnt_in[i] : 0;
    s[threadIdx.x] = x;
    __syncthreads();
    for (int ofs = 1; ofs < 1024; ofs <<= 1) {
        int u = (threadIdx.x >= ofs) ? s[threadIdx.x - ofs] : 0;
        __syncthreads();
        s[threadIdx.x] += u;
        __syncthreads();
    }
    if (i < N_NODES) off_in[i] = s[threadIdx.x] - x;   // local exclusive
    if (threadIdx.x == 1023) bsum[blockIdx.x] = s[1023];
}

// Stage 2: scan 49 block sums (one 64-thread block).
__global__ void scan2(const int* __restrict__ bsum, int* __restrict__ ebase,
                      int* __restrict__ off_in) {
    __shared__ int s[64];
    int t = threadIdx.x;
    int x = (t < SCAN_B) ? bsum[t] : 0;
    s[t] = x;
    __syncthreads();
    for (int ofs = 1; ofs < 64; ofs <<= 1) {
        int u = (t >= ofs) ? s[t - ofs] : 0;
        __syncthreads();
        s[t] += u;
        __syncthreads();
    }
    if (t < SCAN_B) ebase[t] = s[t] - x;
    if (t == 0) off_in[N_NODES] = N_EDGES;
}

// Stage 3: add scanned block bases.
__global__ __launch_bounds__(1024) void
scan3(int* __restrict__ off_in, const int* __restrict__ ebase) {
    int i = blockIdx.x * 1024 + threadIdx.x;
    if (i < N_NODES) off_in[i] += ebase[blockIdx.x];
}

// Scatter edge records into type-sorted slots with final in-CSR positions.
__global__ void place_kernel(const int* __restrict__ src,
                             const int* __restrict__ dst,
                             const int* __restrict__ in_off,
                             const int* __restrict__ rank_in,
                             const int* __restrict__ qe,
                             int* __restrict__ se, int* __restrict__ spi) {
    int e = blockIdx.x * 256 + threadIdx.x;
    if (e < N_EDGES) {
        int q = qe[e];
        if (q < CAP) {                          // guard: never OOB even on 8-sigma
            se[q]  = src[e];
            spi[q] = in_off[dst[e]] + rank_in[e];
        }
    }
}

// MFMA edge kernel, FWD ONLY, bf16 OUTPUT. Wave = 16 same-type edges:
// D[16x32] = H[16x32] @ Wfwd[32x32], 2 n-tiles x 3-split = 6 MFMA.
// C/D layout (m89): row=(l>>4)*4+reg, col=l&15. Messages stored as bf16
// (they are re-quantized to bf16 at the gru MFMA A-operand anyway):
// halves store traffic + gru gather traffic.
__global__ __launch_bounds__(256) void
edge_kernel(const int* __restrict__ se, const int* __restrict__ spi,
            const ushort* __restrict__ wfh, const ushort* __restrict__ wfl,
            const float* __restrict__ prop,
            ushort* __restrict__ fea_in) {
    int wv = blockIdx.x * 4 + (threadIdx.x >> 6);   // wave id; 16 edges each
    int l  = threadIdx.x & 63;
    int slot0 = wv * 16;
    int type = slot0 / CAP_T;                       // wave-uniform (CAP_T%16==0)
    int m  = l & 15;
    int kb = l >> 4;

    // A fragment: h[slot0+m][kb*8 .. kb*8+7] -> split bf16
    int sm = se[slot0 + m];
    const float4* p4 = (const float4*)prop;
    float4 h0 = p4[(size_t)sm * 8 + kb * 2];
    float4 h1 = p4[(size_t)sm * 8 + kb * 2 + 1];
    float hv[8] = {h0.x, h0.y, h0.z, h0.w, h1.x, h1.y, h1.z, h1.w};
    s16x8 ah, al;
    mk_split(hv, ah, al);

    int pr[4];
#pragma unroll
    for (int reg = 0; reg < 4; ++reg) pr[reg] = spi[slot0 + kb * 4 + reg];

    const s16x8* bh8 = (const s16x8*)wfh;
    const s16x8* bl8 = (const s16x8*)wfl;
    f32x4v acc[2];
#pragma unroll
    for (int nt = 0; nt < 2; ++nt) {                // fwd tiles only
        s16x8 bh = bh8[(type * 4 + nt) * 64 + l];
        s16x8 bl = bl8[(type * 4 + nt) * 64 + l];
        f32x4v a = {0.f, 0.f, 0.f, 0.f};
        a = __builtin_amdgcn_mfma_f32_16x16x32_bf16(ah, bh, a, 0, 0, 0);
        a = __builtin_amdgcn_mfma_f32_16x16x32_bf16(al, bh, a, 0, 0, 0);
        a = __builtin_amdgcn_mfma_f32_16x16x32_bf16(ah, bl, a, 0, 0, 0);
        acc[nt] = a;
    }
#pragma unroll
    for (int nt = 0; nt < 2; ++nt)
#pragma unroll
        for (int reg = 0; reg < 4; ++reg)
            fea_in[(size_t)pr[reg] * DD + nt * 16 + m] = f2bf(acc[nt][reg]);
}

// MFMA GRU with factorized out-sums, bf16 in-gather. Order tuned for latency:
// (1) issue in_off/c8/prop loads; (2) dense out-sum MFMAs run under the
// in_off latency window; (3) CSR-gather in-sum (one 16B ushort8 load/row);
// (4) r,z,t matvecs with the 3-term split; r*p transposed via per-wave LDS.
__global__ __launch_bounds__(256) void
gru_kernel(const ushort* __restrict__ wgh, const ushort* __restrict__ wgl,
           const ushort* __restrict__ wfh, const ushort* __restrict__ wfl,
           const float* __restrict__ b_r, const float* __restrict__ b_z,
           const float* __restrict__ b_t,
           const ushort* __restrict__ fea_in,
           const int* __restrict__ in_off,
           const u64* __restrict__ c8,
           float* __restrict__ prop,
           float* __restrict__ out2) {
    __shared__ float tr[4][16 * 36];                  // per-wave transpose pad
    const int wvl = threadIdx.x >> 6;
    const int wv = blockIdx.x * 4 + wvl;
    if (wv * 16 >= N_NODES) return;                   // 3125 waves exact
    const int l = threadIdx.x & 63;
    const int m = l & 15;
    const int kb = l >> 4;
    const int gn = wv * 16 + m;                       // A-row node

    // ---- issue long-latency loads first ----
    int i0 = in_off[gn], i1 = in_off[gn + 1];
    u64 cb[4];
#pragma unroll
    for (int reg = 0; reg < 4; ++reg) cb[reg] = c8[wv * 16 + kb * 4 + reg];
    float pA[8];
    {
        const float4* p4 = (const float4*)prop;
        float4 a = p4[(size_t)gn * 8 + kb * 2];
        float4 b = p4[(size_t)gn * 8 + kb * 2 + 1];
        pA[0] = a.x; pA[1] = a.y; pA[2] = a.z; pA[3] = a.w;
        pA[4] = b.x; pA[5] = b.y; pA[6] = b.z; pA[7] = b.w;
    }
    s16x8 ph, pl;
    mk_split(pA, ph, pl);

    // ---- dense out-sum: 8 types, c-weighted, on the prop fragment ----
    // (runs while in_off/gather loads are in flight)
    const s16x8* eh8 = (const s16x8*)wfh;
    const s16x8* el8 = (const s16x8*)wfl;
    f32x4v outD[2];
    outD[0] = (f32x4v){0.f, 0.f, 0.f, 0.f};
    outD[1] = (f32x4v){0.f, 0.f, 0.f, 0.f};
#pragma unroll 1
    for (int t = 0; t < ETYPES; ++t) {
        s16x8 bh2 = eh8[(t * 4 + 2) * 64 + l];        // rev tiles of W_edge
        s16x8 bl2 = el8[(t * 4 + 2) * 64 + l];
        s16x8 bh3 = eh8[(t * 4 + 3) * 64 + l];
        s16x8 bl3 = el8[(t * 4 + 3) * 64 + l];
        f32x4v a0 = {0.f, 0.f, 0.f, 0.f}, a1 = {0.f, 0.f, 0.f, 0.f};
        a0 = __builtin_amdgcn_mfma_f32_16x16x32_bf16(ph, bh2, a0, 0, 0, 0);
        a0 = __builtin_amdgcn_mfma_f32_16x16x32_bf16(pl, bh2, a0, 0, 0, 0);
        a0 = __builtin_amdgcn_mfma_f32_16x16x32_bf16(ph, bl2, a0, 0, 0, 0);
        a1 = __builtin_amdgcn_mfma_f32_16x16x32_bf16(ph, bh3, a1, 0, 0, 0);
        a1 = __builtin_amdgcn_mfma_f32_16x16x32_bf16(pl, bh3, a1, 0, 0, 0);
        a1 = __builtin_amdgcn_mfma_f32_16x16x32_bf16(ph, bl3, a1, 0, 0, 0);
#pragma unroll
        for (int reg = 0; reg < 4; ++reg) {
            float w = (float)((cb[reg] >> (8 * t)) & 0xff);
            outD[0][reg] = fmaf(w, a0[reg], outD[0][reg]);
            outD[1][reg] = fmaf(w, a1[reg], outD[1][reg]);
        }
    }

    // ---- CSR-gather in-sum (bf16 rows, one 16B load per row) ----
    float va[8];
#pragma unroll
    for (int i = 0; i < 8; ++i) va[i] = 0.f;
    {
        const u16x8* fi8 = (const u16x8*)fea_in;      // row = 4 x ushort8
        for (int r = i0; r < i1; ++r) {
            u16x8 x = fi8[(size_t)r * 4 + kb];
#pragma unroll
            for (int i = 0; i < 8; ++i) va[i] += bf2f(x[i]);
        }
    }

    // ---- transpose out (D-layout -> A-layout) via per-wave LDS ----
    float* T = tr[wvl];
#pragma unroll
    for (int nt = 0; nt < 2; ++nt)
#pragma unroll
        for (int reg = 0; reg < 4; ++reg)
            T[(kb * 4 + reg) * 36 + nt * 16 + m] = outD[nt][reg];
    float oA[8];
    {
        const float4* T4 = (const float4*)(T + m * 36 + kb * 8);
        float4 x = T4[0], y = T4[1];
        oA[0] = x.x; oA[1] = x.y; oA[2] = x.z; oA[3] = x.w;
        oA[4] = y.x; oA[5] = y.y; oA[6] = y.z; oA[7] = y.w;
    }

    s16x8 ah[3], al[3];
    mk_split(va, ah[0], al[0]);
    mk_split(oA, ah[1], al[1]);
    ah[2] = ph; al[2] = pl;

    const s16x8* bh8 = (const s16x8*)wgh;
    const s16x8* bl8 = (const s16x8*)wgl;
    f32x4v ar[2], az[2], at_[2];
#pragma unroll
    for (int nt = 0; nt < 2; ++nt) {
        ar[nt] = (f32x4v){0.f, 0.f, 0.f, 0.f};
        az[nt] = (f32x4v){0.f, 0.f, 0.f, 0.f};
        at_[nt] = (f32x4v){0.f, 0.f, 0.f, 0.f};
    }
#pragma unroll
    for (int nt = 0; nt < 2; ++nt) {
#pragma unroll
        for (int kt = 0; kt < 3; ++kt) {
            s16x8 bh = bh8[((0 * 3 + kt) * 2 + nt) * 64 + l];
            s16x8 bl = bl8[((0 * 3 + kt) * 2 + nt) * 64 + l];
            ar[nt] = __builtin_amdgcn_mfma_f32_16x16x32_bf16(ah[kt], bh, ar[nt], 0, 0, 0);
            ar[nt] = __builtin_amdgcn_mfma_f32_16x16x32_bf16(al[kt], bh, ar[nt], 0, 0, 0);
            ar[nt] = __builtin_amdgcn_mfma_f32_16x16x32_bf16(ah[kt], bl, ar[nt], 0, 0, 0);
            s16x8 ch = bh8[((1 * 3 + kt) * 2 + nt) * 64 + l];
            s16x8 cl = bl8[((1 * 3 + kt) * 2 + nt) * 64 + l];
            az[nt] = __builtin_amdgcn_mfma_f32_16x16x32_bf16(ah[kt], ch, az[nt], 0, 0, 0);
            az[nt] = __builtin_amdgcn_mfma_f32_16x16x32_bf16(al[kt], ch, az[nt], 0, 0, 0);
            az[nt] = __builtin_amdgcn_mfma_f32_16x16x32_bf16(ah[kt], cl, az[nt], 0, 0, 0);
            if (kt < 2) {
                s16x8 th = bh8[((2 * 3 + kt) * 2 + nt) * 64 + l];
                s16x8 tl = bl8[((2 * 3 + kt) * 2 + nt) * 64 + l];
                at_[nt] = __builtin_amdgcn_mfma_f32_16x16x32_bf16(ah[kt], th, at_[nt], 0, 0, 0);
                at_[nt] = __builtin_amdgcn_mfma_f32_16x16x32_bf16(al[kt], th, at_[nt], 0, 0, 0);
                at_[nt] = __builtin_amdgcn_mfma_f32_16x16x32_bf16(ah[kt], tl, at_[nt], 0, 0, 0);
            }
        }
    }

    // ---- bias + sigmoid; r*p and z in D-layout (row=kb*4+reg, col=nt*16+m) --
    float rv[2][4], zv[2][4], pD[2][4];
#pragma unroll
    for (int nt = 0; nt < 2; ++nt) {
        float br = b_r[nt * 16 + m];
        float bz = b_z[nt * 16 + m];
#pragma unroll
        for (int reg = 0; reg < 4; ++reg) {
            int nd = wv * 16 + kb * 4 + reg;
            pD[nt][reg] = prop[(size_t)nd * DD + nt * 16 + m];
            rv[nt][reg] = sigm(ar[nt][reg] + br) * pD[nt][reg];   // r*p
            zv[nt][reg] = sigm(az[nt][reg] + bz);
        }
    }

    // ---- transpose r*p via the same per-wave LDS pad (in-order DS) ----
#pragma unroll
    for (int nt = 0; nt < 2; ++nt)
#pragma unroll
        for (int reg = 0; reg < 4; ++reg)
            T[(kb * 4 + reg) * 36 + nt * 16 + m] = rv[nt][reg];
    float rpA[8];
    {
        const float4* T4 = (const float4*)(T + m * 36 + kb * 8);
        float4 x = T4[0], y = T4[1];
        rpA[0] = x.x; rpA[1] = x.y; rpA[2] = x.z; rpA[3] = x.w;
        rpA[4] = y.x; rpA[5] = y.y; rpA[6] = y.z; rpA[7] = y.w;
    }
    s16x8 rh, rl;
    mk_split(rpA, rh, rl);
#pragma unroll
    for (int nt = 0; nt < 2; ++nt) {
        s16x8 th = bh8[((2 * 3 + 2) * 2 + nt) * 64 + l];
        s16x8 tl = bl8[((2 * 3 + 2) * 2 + nt) * 64 + l];
        at_[nt] = __builtin_amdgcn_mfma_f32_16x16x32_bf16(rh, th, at_[nt], 0, 0, 0);
        at_[nt] = __builtin_amdgcn_mfma_f32_16x16x32_bf16(rl, th, at_[nt], 0, 0, 0);
        at_[nt] = __builtin_amdgcn_mfma_f32_16x16x32_bf16(rh, tl, at_[nt], 0, 0, 0);
    }

    // ---- update: prop = p + z*(tanh(t) - p); final step writes out2 ONLY ----
#pragma unroll
    for (int nt = 0; nt < 2; ++nt) {
        float bt = b_t[nt * 16 + m];
#pragma unroll
        for (int reg = 0; reg < 4; ++reg) {
            int nd = wv * 16 + kb * 4 + reg;
            float tv = fast_tanh(at_[nt][reg] + bt);
            float o = fmaf(zv[nt][reg], tv - pD[nt][reg], pD[nt][reg]);
            if (out2) out2[(size_t)nd * DD + nt * 16 + m] = o;
            else      prop[(size_t)nd * DD + nt * 16 + m] = o;
        }
    }
}

extern "C" void kernel_launch(void* const* d_in, const int* in_sizes, int n_in,
                              void* d_out, int out_size, void* d_ws, size_t ws_size,
                              hipStream_t stream) {
    const int*   token  = (const int*)d_in[0];
    const int*   etype  = (const int*)d_in[1];
    const int*   src    = (const int*)d_in[2];
    const int*   dst    = (const int*)d_in[3];
    const float* emb    = (const float*)d_in[4];
    const float* W_edge = (const float*)d_in[5];
    const float* W_r    = (const float*)d_in[6];
    const float* b_r    = (const float*)d_in[7];
    const float* W_z    = (const float*)d_in[8];
    const float* b_z    = (const float*)d_in[9];
    const float* W_t    = (const float*)d_in[10];
    const float* b_t    = (const float*)d_in[11];
    float* out = (float*)d_out;

    // Persistent workspace (~15 MB; ws_size = 256 MB per the poison fill):
    float* prop      = (float*)d_ws;                          // N*D floats
    ushort* fea_in   = (ushort*)(prop + (size_t)N_NODES * DD);// (E+1)*D bf16
    ushort* wfh = fea_in + (size_t)(N_EDGES + 1) * DD;        // 16K ushorts
    ushort* wfl = wfh + ETYPES * 4 * 64 * 8;                  // 16K
    ushort* wgh = wfl + ETYPES * 4 * 64 * 8;                  // 9216
    ushort* wgl = wgh + 1152 * 8;                             // 9216
    u64* c8     = (u64*)(wgl + 1152 * 8);                     // N u64 (8B-aligned)
    int* in_off   = (int*)(c8 + N_NODES);                     // N+1
    int* se       = in_off + (N_NODES + 1);                   // CAP
    int* spi      = se + CAP;                                 // CAP

    // Setup temporaries OVERLAID on fea_in (dead before first edge write).
    int* cnt      = (int*)fea_in;                             // N+8
    int* cnt_in   = cnt;
    int* tcnt     = cnt + N_NODES;
    int* rank_in  = cnt + N_NODES + ETYPES;                   // E
    int* qe       = rank_in + N_EDGES;                        // E
    int* bsum     = qe + N_EDGES;                             // SCAN_B
    int* ebase    = bsum + SCAN_B;                            // SCAN_B

    // per-launch setup: prop init + W fragments + type-bucketed in-CSR build
    init_kernel<<<(N_NODES * DD) / 256, 256, 0, stream>>>(token, emb, prop, cnt,
                                                          c8, se, spi);
    wfrag_kernel<<<13, 256, 0, stream>>>(W_edge, W_r, W_z, W_t,
                                         wfh, wfl, wgh, wgl);
    hist_kernel<<<(N_EDGES + 255) / 256, 256, 0, stream>>>(
        etype, src, dst, cnt_in, tcnt, c8, rank_in, qe);
    scan1<<<SCAN_B, 1024, 0, stream>>>(cnt_in, in_off, bsum);
    scan2<<<1, 64, 0, stream>>>(bsum, ebase, in_off);
    scan3<<<SCAN_B, 1024, 0, stream>>>(in_off, ebase);
    place_kernel<<<(N_EDGES + 255) / 256, 256, 0, stream>>>(
        src, dst, in_off, rank_in, qe, se, spi);

    for (int step = 0; step < STEPS; ++step) {
        edge_kernel<<<CAP / 64, 256, 0, stream>>>(se, spi, wfh, wfl, prop,
                                                  fea_in);
        gru_kernel<<<GRU_GRID, 256, 0, stream>>>(
            wgh, wgl, wfh, wfl, b_r, b_z, b_t, fea_in, in_off, c8,
            prop, (step == STEPS - 1) ? out : nullptr);
    }
}